// Round 6
// baseline (87.293 us; speedup 1.0000x reference)
//
#include <hip/hip_runtime.h>

typedef __attribute__((ext_vector_type(8))) short short8;
typedef __attribute__((ext_vector_type(4))) float f32x4;

#define T_DIM 4096
#define C_DIM 128
#define U_DIM 256
#define BM 64
#define NR 68            // staged LDS rows (4-row load granularity), rows t0-1..t0+66
#define TP2 4098         // padded rows per batch in xbf: [zero, t=0..4095, zero]

__device__ __forceinline__ unsigned short f2bf(float f) {
    unsigned int u = __float_as_uint(f);
    u += 0x7FFFu + ((u >> 16) & 1u);   // round-to-nearest-even
    return (unsigned short)(u >> 16);
}

// ---------------- kernel 1: convert+norm (16384 blocks) + wfrag pack (48) + scalars (1)
// xbf layout: per batch TP2 rows of 128 bf16 (256 B). Within a row, 16B chunks are
// pre-swizzled: data chunk c stored at position c ^ ((t+1)&7)  (t = global row; row
// r_lds in a tile has (t+1)&7 == r_lds&7 since tiles are 64-aligned).
__global__ __launch_bounds__(320) void prep_all(
        const float* __restrict__ inp, const float* __restrict__ w,
        const float* __restrict__ b, const float* __restrict__ p,
        const float* __restrict__ q,
        unsigned short* __restrict__ xbf, unsigned short* __restrict__ wfrag,
        float* __restrict__ xninv, float* __restrict__ winv,
        float* __restrict__ p2, float* __restrict__ bc) {
    const int blk = blockIdx.x;
    const int tid = threadIdx.x;
    if (blk < 16384) {
        __shared__ float ss_s[10];
        const int bb    = blk >> 9;            // 512 blocks per batch
        const int tbase = (blk & 511) * 8;     // 8 output rows per block
        const int gidx  = tid >> 5;            // 0..9 (rows tbase-1 .. tbase+8)
        const int hl    = tid & 31;
        const int t     = tbase - 1 + gidx;
        float4 v = make_float4(0.f, 0.f, 0.f, 0.f);
        if ((unsigned)t < T_DIM)
            v = *(const float4*)(inp + ((size_t)bb * T_DIM + t) * C_DIM + hl * 4);
        float part = v.x * v.x + v.y * v.y + v.z * v.z + v.w * v.w;
        #pragma unroll
        for (int o = 16; o > 0; o >>= 1) part += __shfl_xor(part, o, 32);
        if (hl == 0) ss_s[gidx] = part;
        if ((unsigned)t < T_DIM) {
            int c  = hl >> 1;                  // 16B chunk index 0..15
            int cs = c ^ ((t + 1) & 7);        // swizzled position
            ushort4 sv;
            sv.x = f2bf(v.x); sv.y = f2bf(v.y); sv.z = f2bf(v.z); sv.w = f2bf(v.w);
            *(ushort4*)(xbf + ((size_t)bb * TP2 + t + 1) * 128 + cs * 8 + (hl & 1) * 4) = sv;
        }
        if (tbase == 0 && tid < 32) {          // zero pad row t=-1
            ushort4 z = make_ushort4(0, 0, 0, 0);
            ((ushort4*)(xbf + (size_t)bb * TP2 * 128))[tid] = z;
        }
        if (tbase == T_DIM - 8 && tid < 32) {  // zero pad row t=T
            ushort4 z = make_ushort4(0, 0, 0, 0);
            ((ushort4*)(xbf + ((size_t)bb * TP2 + T_DIM + 1) * 128))[tid] = z;
        }
        __syncthreads();
        if (tid < 8) {
            float q2v = q[0] * q[0];
            float s3  = ss_s[tid] + ss_s[tid + 1] + ss_s[tid + 2];
            xninv[(size_t)bb * T_DIM + tbase + tid] =
                1.0f / (sqrtf(fmaxf(s3, 1e-12f)) + q2v);
        }
    } else if (blk < 16432) {
        if (tid < 256) {
            int idx = (blk - 16384) * 256 + tid;    // 0..12287 lane-frags
            int ll = idx & 63;
            int nt = (idx >> 6) & 15;
            int ks = idx >> 10;                     // 0..11
            int n  = nt * 16 + (ll & 15);
            int k0 = ks * 32 + ((ll >> 4) << 3);
            #pragma unroll
            for (int j = 0; j < 8; ++j)
                wfrag[(size_t)idx * 8 + j] = f2bf(w[(k0 + j) * U_DIM + n]);
        }
    } else {
        if (tid < 256) {
            int u = tid;
            float ss = 0.f;
            for (int k = 0; k < 3 * C_DIM; ++k) {
                float v = w[k * U_DIM + u];
                ss += v * v;
            }
            float q2v = q[0] * q[0];
            winv[u] = 1.0f / (sqrtf(fmaxf(ss, 1e-12f)) + q2v);
            float pv = p[u];
            p2[u] = pv * pv;
            bc[u] = b[u];
        }
    }
}

// ---------------- kernel 2: lean MFMA main. global_load_lds staging, one barrier.
__global__ __launch_bounds__(256, 4) void cossim_main(
        const unsigned short* __restrict__ xbf,
        const unsigned short* __restrict__ wfrag,
        const float* __restrict__ xninv,
        const float* __restrict__ winv,
        const float* __restrict__ p2g,
        const float* __restrict__ bg,
        float* __restrict__ out) {
    __shared__ unsigned short xs[NR * 128];    // 17408 B, swizzled rows

    const int tid = threadIdx.x;
    const int bb  = blockIdx.x >> 6;           // batch
    const int t0  = (blockIdx.x & 63) * BM;    // tile start
    const int wid = tid >> 6;                  // wave id = u quarter
    const int l   = tid & 63;
    const int l15 = l & 15;
    const int lg  = l >> 4;

    // ---- stage 68 rows (17 KB) via global_load_lds: rows t0-1.. -> xbf rows t0.. ----
    {
        const unsigned short* src = xbf + ((size_t)bb * TP2 + t0) * 128;
        for (int j = wid; j < 17; j += 4) {
            const unsigned short* gp = src + j * 512 + l * 8;   // per-lane 16 B
            __builtin_amdgcn_global_load_lds(
                (const __attribute__((address_space(1))) unsigned int*)gp,
                (__attribute__((address_space(3))) unsigned int*)(xs + j * 512),
                16, 0, 0);
        }
    }
    __syncthreads();

    // ---- MFMA: each wave 64(t) x 64(u); A = w frag, B = x frag; D[u][t] ----
    f32x4 acc[4][4];                           // [tf][uf]
    #pragma unroll
    for (int tf = 0; tf < 4; ++tf)
        #pragma unroll
        for (int uf = 0; uf < 4; ++uf)
            acc[tf][uf] = (f32x4){0.f, 0.f, 0.f, 0.f};

    const short8* wf = (const short8*)wfrag;

    #pragma unroll
    for (int ks = 0; ks < 12; ++ks) {
        const int tap = ks >> 2;
        const int cb  = (ks & 3) * 4;          // base 16B-chunk within row
        short8 xv[4], wvv[4];
        #pragma unroll
        for (int tf = 0; tf < 4; ++tf) {
            int r  = tf * 16 + l15 + tap;      // LDS row (= t - t0 + 1)
            int ch = (cb + lg) ^ (r & 7);      // un-swizzle
            xv[tf] = *(const short8*)(xs + r * 128 + ch * 8);
        }
        #pragma unroll
        for (int uf = 0; uf < 4; ++uf)
            wvv[uf] = wf[(size_t)(ks * 16 + wid * 4 + uf) * 64 + l];
        #pragma unroll
        for (int tf = 0; tf < 4; ++tf)
            #pragma unroll
            for (int uf = 0; uf < 4; ++uf)
                acc[tf][uf] = __builtin_amdgcn_mfma_f32_16x16x32_bf16(
                    wvv[uf], xv[tf], acc[tf][uf], 0, 0, 0);
    }

    // ---- epilogue: lane holds 4 consecutive u at fixed t -> dwordx4 stores ----
    #pragma unroll
    for (int tf = 0; tf < 4; ++tf) {
        int trow = t0 + tf * 16 + l15;
        float xi = xninv[(size_t)bb * T_DIM + trow];
        float* orow = out + ((size_t)bb * T_DIM + trow) * U_DIM;
        #pragma unroll
        for (int uf = 0; uf < 4; ++uf) {
            int uc = wid * 64 + uf * 16 + lg * 4;
            f32x4 wiv = *(const f32x4*)(winv + uc);
            f32x4 ppv = *(const f32x4*)(p2g + uc);
            f32x4 bbv = *(const f32x4*)(bg + uc);
            f32x4 r;
            #pragma unroll
            for (int j = 0; j < 4; ++j) {
                float raw = acc[tf][uf][j];
                float y   = raw * xi * wiv[j];
                float ay  = fabsf(y) + 1e-12f;
                float pw  = ppv[j];
                float rr  = ay;
                if (pw != 1.0f) rr = powf(ay, pw);   // p==1 at runtime: branch skipped
                float s   = (raw > 0.f) ? 1.f : ((raw < 0.f) ? -1.f : 0.f);
                r[j] = s * rr + bbv[j];
            }
            *(f32x4*)(orow + uc) = r;
        }
    }
}

extern "C" void kernel_launch(void* const* d_in, const int* in_sizes, int n_in,
                              void* d_out, int out_size, void* d_ws, size_t ws_size,
                              hipStream_t stream) {
    const float* inp = (const float*)d_in[0];
    const float* w   = (const float*)d_in[1];
    const float* b   = (const float*)d_in[2];
    const float* p   = (const float*)d_in[3];
    const float* q   = (const float*)d_in[4];
    float* out = (float*)d_out;

    // ws layout
    unsigned short* xbf   = (unsigned short*)d_ws;                       // 32*4098*256 B = 33,570,816
    unsigned short* wfrag = (unsigned short*)((char*)d_ws + 33570816);   // 196,608 B
    float* xninv = (float*)((char*)d_ws + 33570816 + 196608);            // 524,288 B
    float* winv  = xninv + 32 * 4096;
    float* p2    = winv + 256;
    float* bc    = p2 + 256;

    prep_all<<<16433, 320, 0, stream>>>(inp, w, b, p, q, xbf, wfrag, xninv, winv, p2, bc);
    cossim_main<<<2048, 256, 0, stream>>>(xbf, wfrag, xninv, winv, p2, bc, out);
}